// Round 2
// baseline (556.915 us; speedup 1.0000x reference)
//
#include <hip/hip_runtime.h>
#include <math.h>

// ---------------------------------------------------------------------------
// DynamicAttention4 (B=32 L=256 S=T=64 H=768 Q=768 F=1024 OUT=768)
// q=query@Wq+bq; s_key=src@Ws+bs; t_key=trg@Wt+bt
// rel_key[b,t,s,:]=tanh(s_key[b,s,:]+t_key[b,t,:])   (NOT materialized)
// scores[b,l,ts]=q·rel_key/sqrt(768); softmax over ts=4096
// ctx[b,l,:]=sum_ts w*rel_key; out=relu([query,ctx]@Wo+bo)
// rel_key is fused into both attention GEMMs (tanh computed from staged
// s_key/t_key tiles in LDS). Workspace ~145 MB.
// ---------------------------------------------------------------------------

typedef __attribute__((ext_vector_type(8))) short bf16x8;
typedef __attribute__((ext_vector_type(4))) float f32x4;

__device__ __forceinline__ unsigned short f2bf(float f) {
    union { float f; unsigned u; } x; x.f = f;
    unsigned u = x.u;
    return (unsigned short)((u + 0x7fffu + ((u >> 16) & 1u)) >> 16);
}
__device__ __forceinline__ float bf2f(unsigned short h) {
    union { unsigned u; float f; } x; x.u = (unsigned)h << 16;
    return x.f;
}
__device__ __forceinline__ float tanh_fast(float x) {
    // tanh(x) = 1 - 2/(1+e^{2x}); handles +-inf correctly.
    float e = __expf(2.0f * x);
    return 1.0f - 2.0f * __builtin_amdgcn_rcpf(1.0f + e);
}
__device__ __forceinline__ void async_copy16(void* lds, const void* g) {
    __builtin_amdgcn_global_load_lds(
        (const __attribute__((address_space(1))) unsigned int*)g,
        (__attribute__((address_space(3))) unsigned int*)lds,
        16, 0, 0);
}

// ---------------------------------------------------------------------------
// Generic bf16 BT-GEMM: C[m,n] = sum_k A[m,k]*BT[n,k] (+bias,+relu)
// 128x128 tile, BK=32, 4 waves, 4x4 16x16x32 frags. Same k-map for A/B.
// ---------------------------------------------------------------------------
template<bool OUT_BF16, bool RELU>
__global__ __launch_bounds__(256, 2) void gemm_bt_kernel(
    const unsigned short* __restrict__ A, const unsigned short* __restrict__ BT,
    void* __restrict__ Cout, const float* __restrict__ bias,
    int M, int N, int K, int lda, int ldb, int ldc)
{
    __shared__ unsigned short As[128 * 32];
    __shared__ unsigned short Bs[128 * 32];
    const int m0 = blockIdx.x * 128, n0 = blockIdx.y * 128;
    const int tid = threadIdx.x;
    const int lane = tid & 63, wid = tid >> 6;
    const int wr = wid >> 1, wc = wid & 1;
    const int r = lane & 15, g = lane >> 4;

    f32x4 acc[4][4] = {};

    for (int k0 = 0; k0 < K; k0 += 32) {
        __syncthreads();
        #pragma unroll
        for (int j = 0; j < 2; ++j) {
            int c = j * 256 + tid;
            int row = c >> 2, kc = (c & 3) * 8;
            async_copy16(&As[c * 8], A  + (size_t)(m0 + row) * lda + k0 + kc);
            async_copy16(&Bs[c * 8], BT + (size_t)(n0 + row) * ldb + k0 + kc);
        }
        asm volatile("s_waitcnt vmcnt(0)" ::: "memory");
        __syncthreads();

        bf16x8 af[4], bfr[4];
        #pragma unroll
        for (int m = 0; m < 4; ++m)
            af[m] = *(const bf16x8*)&As[(wr * 64 + m * 16 + r) * 32 + g * 8];
        #pragma unroll
        for (int n = 0; n < 4; ++n)
            bfr[n] = *(const bf16x8*)&Bs[(wc * 64 + n * 16 + r) * 32 + g * 8];
        #pragma unroll
        for (int m = 0; m < 4; ++m)
            #pragma unroll
            for (int n = 0; n < 4; ++n)
                acc[m][n] = __builtin_amdgcn_mfma_f32_16x16x32_bf16(
                    af[m], bfr[n], acc[m][n], 0, 0, 0);
    }

    float* Cf = (float*)Cout;
    unsigned short* Cb = (unsigned short*)Cout;
    #pragma unroll
    for (int n = 0; n < 4; ++n) {
        int col = n0 + wc * 64 + n * 16 + r;
        float bv = bias ? bias[col] : 0.0f;
        #pragma unroll
        for (int m = 0; m < 4; ++m) {
            int row0 = m0 + wr * 64 + m * 16 + g * 4;
            #pragma unroll
            for (int i = 0; i < 4; ++i) {
                float v = acc[m][n][i] + bv;
                if (RELU) v = fmaxf(v, 0.0f);
                size_t off = (size_t)(row0 + i) * ldc + col;
                if (OUT_BF16) Cb[off] = f2bf(v);
                else          Cf[off] = v;
            }
        }
    }
}

// ---------------------------------------------------------------------------
// scores[b,l,ts] GEMM with fused rel_key B-tiles.
// A = qh[b] (256x768 bf16), B[n=ts][k=h] = tanh(s_key[s,h]+t_key[t,h]).
// grid (2, 32, 32) = (m-tiles, ts-tiles, batch)
// ---------------------------------------------------------------------------
__global__ __launch_bounds__(256, 2) void scores_kernel(
    const unsigned short* __restrict__ qh,   // [32][256][768]
    const float* __restrict__ s_key,         // [32][64][768]
    const float* __restrict__ t_key,         // [32][64][768]
    unsigned short* __restrict__ scores)     // [32][256][4096]
{
    __shared__ unsigned short As[128 * 32];
    __shared__ unsigned short Bs[128 * 32];
    __shared__ float Sk[64 * 32];
    __shared__ float Tk[64];

    const int b = blockIdx.z;
    const unsigned short* A = qh + (size_t)b * 256 * 768;
    const float* skp = s_key + (size_t)b * 64 * 768;
    const float* tkp = t_key + (size_t)b * 64 * 768;
    const int m0 = blockIdx.x * 128, n0 = blockIdx.y * 128;
    const int t0 = n0 >> 6;                  // two t values per 128-ts tile
    const int tid = threadIdx.x;
    const int lane = tid & 63, wid = tid >> 6;
    const int wr = wid >> 1, wc = wid & 1;
    const int r = lane & 15, g = lane >> 4;

    f32x4 acc[4][4] = {};

    for (int k0 = 0; k0 < 768; k0 += 32) {
        __syncthreads();
        if (tid < 64) Tk[tid] = tkp[(size_t)(t0 + (tid >> 5)) * 768 + k0 + (tid & 31)];
        #pragma unroll
        for (int j = 0; j < 2; ++j) {
            int c = j * 256 + tid;
            int row = c >> 2, kc = (c & 3) * 8;
            async_copy16(&As[c * 8], A + (size_t)(m0 + row) * 768 + k0 + kc);
            int s = c >> 3, k4 = (c & 7) * 4;
            async_copy16(&Sk[s * 32 + k4], skp + (size_t)s * 768 + k0 + k4);
        }
        asm volatile("s_waitcnt vmcnt(0)" ::: "memory");
        __syncthreads();

        // Bs[n][kk] = bf16(tanh(Sk[n&63][kk] + Tk[n>>6][kk]))
        #pragma unroll
        for (int j = 0; j < 2; ++j) {
            int c = j * 256 + tid;
            int n = c >> 2, kc = (c & 3) * 8;
            const float* sv = &Sk[(n & 63) * 32 + kc];
            const float* tv = &Tk[(n >> 6) * 32 + kc];
            bf16x8 o;
            #pragma unroll
            for (int e = 0; e < 8; ++e)
                o[e] = (short)f2bf(tanh_fast(sv[e] + tv[e]));
            *(bf16x8*)&Bs[n * 32 + kc] = o;
        }
        __syncthreads();

        bf16x8 af[4], bfr[4];
        #pragma unroll
        for (int m = 0; m < 4; ++m)
            af[m] = *(const bf16x8*)&As[(wr * 64 + m * 16 + r) * 32 + g * 8];
        #pragma unroll
        for (int n = 0; n < 4; ++n)
            bfr[n] = *(const bf16x8*)&Bs[(wc * 64 + n * 16 + r) * 32 + g * 8];
        #pragma unroll
        for (int m = 0; m < 4; ++m)
            #pragma unroll
            for (int n = 0; n < 4; ++n)
                acc[m][n] = __builtin_amdgcn_mfma_f32_16x16x32_bf16(
                    af[m], bfr[n], acc[m][n], 0, 0, 0);
    }

    unsigned short* C = scores + (size_t)b * 256 * 4096;
    #pragma unroll
    for (int n = 0; n < 4; ++n) {
        int col = n0 + wc * 64 + n * 16 + r;
        #pragma unroll
        for (int m = 0; m < 4; ++m) {
            int row0 = m0 + wr * 64 + m * 16 + g * 4;
            #pragma unroll
            for (int i = 0; i < 4; ++i)
                C[(size_t)(row0 + i) * 4096 + col] = f2bf(acc[m][n][i]);
        }
    }
}

// ---------------------------------------------------------------------------
// ctx[b,l,h] GEMM with fused rel_key B-tiles (transposed access).
// A = w[b] (256x4096 bf16), B[n=h][k=ts] = tanh(s_keyT[h,s]+t_keyT[h,t]).
// Writes bf16 into xcat[:, 768:1536]. grid (2, 6, 32).
// ---------------------------------------------------------------------------
__global__ __launch_bounds__(256, 2) void ctx_kernel(
    const unsigned short* __restrict__ w,    // [32][256][4096] (normalized)
    const float* __restrict__ s_keyT,        // [32][768][64]
    const float* __restrict__ t_keyT,        // [32][768][64]
    unsigned short* __restrict__ xcat)       // [8192][1536]
{
    __shared__ unsigned short As[128 * 32];
    __shared__ unsigned short Bs[128 * 32];
    __shared__ float SkT[128 * 32];          // [h][32 s-chunk] fp32
    __shared__ unsigned short TkTb[128 * 64];// [h][t] bf16 (whole block slab)

    const int b = blockIdx.z;
    const unsigned short* A = w + (size_t)b * 256 * 4096;
    const float* skT = s_keyT + (size_t)b * 768 * 64;
    const float* tkT = t_keyT + (size_t)b * 768 * 64;
    const int m0 = blockIdx.x * 128, n0 = blockIdx.y * 128;
    const int tid = threadIdx.x;
    const int lane = tid & 63, wid = tid >> 6;
    const int wr = wid >> 1, wc = wid & 1;
    const int r = lane & 15, g = lane >> 4;

    // prestage t_keyT slab for this h-tile: [128][64] -> bf16
    for (int j = tid; j < 128 * 64; j += 256)
        TkTb[j] = f2bf(tkT[(size_t)n0 * 64 + j]);

    f32x4 acc[4][4] = {};

    for (int k0 = 0; k0 < 4096; k0 += 32) {
        const int t = k0 >> 6, s0 = k0 & 63;   // ts = t*64 + (s0..s0+31)
        __syncthreads();
        #pragma unroll
        for (int j = 0; j < 2; ++j) {
            int c = j * 256 + tid;
            int row = c >> 2, kc = (c & 3) * 8;
            async_copy16(&As[c * 8], A + (size_t)(m0 + row) * 4096 + k0 + kc);
        }
        #pragma unroll
        for (int j = 0; j < 4; ++j) {
            int c = j * 256 + tid;
            int h = c >> 3, k4 = (c & 7) * 4;
            async_copy16(&SkT[h * 32 + k4], skT + (size_t)(n0 + h) * 64 + s0 + k4);
        }
        asm volatile("s_waitcnt vmcnt(0)" ::: "memory");
        __syncthreads();

        // Bs[h][kk] = bf16(tanh(SkT[h][kk] + TkT[h][t]))
        #pragma unroll
        for (int j = 0; j < 2; ++j) {
            int c = j * 256 + tid;
            int h = c >> 2, kc = (c & 3) * 8;
            const float* sv = &SkT[h * 32 + kc];
            float tval = bf2f(TkTb[h * 64 + t]);
            bf16x8 o;
            #pragma unroll
            for (int e = 0; e < 8; ++e)
                o[e] = (short)f2bf(tanh_fast(sv[e] + tval));
            *(bf16x8*)&Bs[h * 32 + kc] = o;
        }
        __syncthreads();

        bf16x8 af[4], bfr[4];
        #pragma unroll
        for (int m = 0; m < 4; ++m)
            af[m] = *(const bf16x8*)&As[(wr * 64 + m * 16 + r) * 32 + g * 8];
        #pragma unroll
        for (int n = 0; n < 4; ++n)
            bfr[n] = *(const bf16x8*)&Bs[(wc * 64 + n * 16 + r) * 32 + g * 8];
        #pragma unroll
        for (int m = 0; m < 4; ++m)
            #pragma unroll
            for (int n = 0; n < 4; ++n)
                acc[m][n] = __builtin_amdgcn_mfma_f32_16x16x32_bf16(
                    af[m], bfr[n], acc[m][n], 0, 0, 0);
    }

    unsigned short* C = xcat + (size_t)b * 256 * 1536 + 768;
    #pragma unroll
    for (int n = 0; n < 4; ++n) {
        int col = n0 + wc * 64 + n * 16 + r;
        #pragma unroll
        for (int m = 0; m < 4; ++m) {
            int row0 = m0 + wr * 64 + m * 16 + g * 4;
            #pragma unroll
            for (int i = 0; i < 4; ++i)
                C[(size_t)(row0 + i) * 1536 + col] = f2bf(acc[m][n][i]);
        }
    }
}

// ---------------------------------------------------------------------------
// converters / transposes
// ---------------------------------------------------------------------------
__global__ void cvt_bf16_kernel(const float* __restrict__ in,
                                unsigned short* __restrict__ out, int n4) {
    int i = blockIdx.x * 256 + threadIdx.x;
    if (i >= n4) return;
    float4 v = ((const float4*)in)[i];
    ushort4 o;
    o.x = f2bf(v.x); o.y = f2bf(v.y); o.z = f2bf(v.z); o.w = f2bf(v.w);
    ((ushort4*)out)[i] = o;
}

__global__ void cvt_query_kernel(const float* __restrict__ in,
                                 unsigned short* __restrict__ xcat) {
    int i = blockIdx.x * 256 + threadIdx.x;   // 8192*192 float4s
    if (i >= 8192 * 192) return;
    int row = i / 192, c4 = (i % 192) * 4;
    float4 v = ((const float4*)in)[i];
    ushort4 o;
    o.x = f2bf(v.x); o.y = f2bf(v.y); o.z = f2bf(v.z); o.w = f2bf(v.w);
    *(ushort4*)&xcat[(size_t)row * 1536 + c4] = o;
}

__global__ void transpose_w_kernel(const float* __restrict__ in,
                                   unsigned short* __restrict__ out,
                                   int R, int C) {
    __shared__ float tile[64][65];
    const int r0 = blockIdx.y * 64, c0 = blockIdx.x * 64;
    const int tx = threadIdx.x & 63, ty = threadIdx.x >> 6;
    for (int i = ty; i < 64; i += 4)
        tile[i][tx] = in[(size_t)(r0 + i) * C + c0 + tx];
    __syncthreads();
    for (int i = ty; i < 64; i += 4)
        out[(size_t)(c0 + i) * R + r0 + tx] = f2bf(tile[tx][i]);
}

// fp32 [32][64][768] -> fp32 [32][768][64]
__global__ void transpose_sk_kernel(const float* __restrict__ in,
                                    float* __restrict__ out) {
    __shared__ float tile[64][65];
    const int b = blockIdx.y, c0 = blockIdx.x * 64;
    const float* src = in + (size_t)b * 64 * 768;
    float* dst = out + (size_t)b * 768 * 64;
    const int tx = threadIdx.x & 63, ty = threadIdx.x >> 6;
    for (int i = ty; i < 64; i += 4)
        tile[i][tx] = src[(size_t)i * 768 + c0 + tx];
    __syncthreads();
    for (int i = ty; i < 64; i += 4)
        dst[(size_t)(c0 + i) * 64 + tx] = tile[tx][i];
}

// ---------------------------------------------------------------------------
// row softmax over 4096 (bf16 in-place), scale 1/sqrt(768) before exp
// ---------------------------------------------------------------------------
__global__ __launch_bounds__(256) void softmax_kernel(unsigned short* __restrict__ scores) {
    unsigned short* p = scores + (size_t)blockIdx.x * 4096;
    const int tid = threadIdx.x, lane = tid & 63, wid = tid >> 6;
    __shared__ float red[4];

    float v[16];
    {
        const bf16x8* p8 = (const bf16x8*)p;
        bf16x8 a = p8[tid * 2], c = p8[tid * 2 + 1];
        #pragma unroll
        for (int e = 0; e < 8; ++e) {
            v[e]     = bf2f((unsigned short)a[e]);
            v[8 + e] = bf2f((unsigned short)c[e]);
        }
    }
    float mx = v[0];
    #pragma unroll
    for (int e = 1; e < 16; ++e) mx = fmaxf(mx, v[e]);
    #pragma unroll
    for (int o = 32; o; o >>= 1) mx = fmaxf(mx, __shfl_xor(mx, o));
    if (lane == 0) red[wid] = mx;
    __syncthreads();
    mx = fmaxf(fmaxf(red[0], red[1]), fmaxf(red[2], red[3]));
    __syncthreads();

    const float scale = 0.03608439182435161f;   // 1/sqrt(768)
    float sum = 0.0f;
    #pragma unroll
    for (int e = 0; e < 16; ++e) {
        v[e] = __expf((v[e] - mx) * scale);
        sum += v[e];
    }
    #pragma unroll
    for (int o = 32; o; o >>= 1) sum += __shfl_xor(sum, o);
    if (lane == 0) red[wid] = sum;
    __syncthreads();
    sum = red[0] + red[1] + red[2] + red[3];
    const float inv = 1.0f / sum;

    bf16x8* p8 = (bf16x8*)p;
    #pragma unroll
    for (int j = 0; j < 2; ++j) {
        bf16x8 o;
        #pragma unroll
        for (int e = 0; e < 8; ++e)
            o[e] = (short)f2bf(v[j * 8 + e] * inv);
        p8[tid * 2 + j] = o;
    }
}

// ---------------------------------------------------------------------------
extern "C" void kernel_launch(void* const* d_in, const int* in_sizes, int n_in,
                              void* d_out, int out_size, void* d_ws, size_t ws_size,
                              hipStream_t stream) {
    const float* query = (const float*)d_in[0];
    const float* src   = (const float*)d_in[1];
    const float* trg   = (const float*)d_in[2];
    const float* Wq    = (const float*)d_in[3];
    const float* b_q   = (const float*)d_in[4];
    const float* Ws    = (const float*)d_in[5];
    const float* b_s   = (const float*)d_in[6];
    const float* Wt    = (const float*)d_in[7];
    const float* b_t   = (const float*)d_in[8];
    const float* Wo    = (const float*)d_in[9];
    const float* b_o   = (const float*)d_in[10];

    char* ws = (char*)d_ws;
    size_t off = 0;
    auto alloc = [&](size_t bytes) {
        void* p = ws + off;
        off += (bytes + 255) & ~(size_t)255;
        return p;
    };
    unsigned short* xcat   = (unsigned short*)alloc((size_t)8192 * 1536 * 2);
    unsigned short* srcbf  = (unsigned short*)alloc((size_t)2048 * 1024 * 2);
    unsigned short* trgbf  = (unsigned short*)alloc((size_t)2048 * 1024 * 2);
    unsigned short* WqT    = (unsigned short*)alloc((size_t)768 * 768 * 2);
    unsigned short* WsT    = (unsigned short*)alloc((size_t)768 * 1024 * 2);
    unsigned short* WtT    = (unsigned short*)alloc((size_t)768 * 1024 * 2);
    unsigned short* WoT    = (unsigned short*)alloc((size_t)768 * 1536 * 2);
    unsigned short* qh     = (unsigned short*)alloc((size_t)8192 * 768 * 2);
    float*          s_key  = (float*)alloc((size_t)2048 * 768 * 4);
    float*          t_key  = (float*)alloc((size_t)2048 * 768 * 4);
    float*          s_keyT = (float*)alloc((size_t)32 * 768 * 64 * 4);
    float*          t_keyT = (float*)alloc((size_t)32 * 768 * 64 * 4);
    unsigned short* scores = (unsigned short*)alloc((size_t)32 * 256 * 4096 * 2);
    // total ~145 MB

    // 1. input converts
    cvt_query_kernel<<<6144, 256, 0, stream>>>(query, xcat);
    cvt_bf16_kernel<<<2048, 256, 0, stream>>>(src, srcbf, 524288);
    cvt_bf16_kernel<<<2048, 256, 0, stream>>>(trg, trgbf, 524288);

    // 2. weight transposes
    transpose_w_kernel<<<dim3(12, 12), 256, 0, stream>>>(Wq, WqT, 768, 768);
    transpose_w_kernel<<<dim3(12, 16), 256, 0, stream>>>(Ws, WsT, 1024, 768);
    transpose_w_kernel<<<dim3(12, 16), 256, 0, stream>>>(Wt, WtT, 1024, 768);
    transpose_w_kernel<<<dim3(12, 24), 256, 0, stream>>>(Wo, WoT, 1536, 768);

    // 3. projections
    gemm_bt_kernel<true, false><<<dim3(64, 6), 256, 0, stream>>>(
        xcat, WqT, qh, b_q, 8192, 768, 768, 1536, 768, 768);
    gemm_bt_kernel<false, false><<<dim3(16, 6), 256, 0, stream>>>(
        srcbf, WsT, s_key, b_s, 2048, 768, 1024, 1024, 1024, 768);
    gemm_bt_kernel<false, false><<<dim3(16, 6), 256, 0, stream>>>(
        trgbf, WtT, t_key, b_t, 2048, 768, 1024, 1024, 1024, 768);

    // 4. key transposes (fp32, tiny)
    transpose_sk_kernel<<<dim3(12, 32), 256, 0, stream>>>(s_key, s_keyT);
    transpose_sk_kernel<<<dim3(12, 32), 256, 0, stream>>>(t_key, t_keyT);

    // 5. scores (fused rel_key), bf16
    scores_kernel<<<dim3(2, 32, 32), 256, 0, stream>>>(qh, s_key, t_key, scores);

    // 6. softmax in-place
    softmax_kernel<<<8192, 256, 0, stream>>>(scores);

    // 7. ctx (fused rel_key) -> xcat[:, 768:]
    ctx_kernel<<<dim3(2, 6, 32), 256, 0, stream>>>(scores, s_keyT, t_keyT, xcat);

    // 8. out = relu(xcat @ WoT^T + b_o)
    gemm_bt_kernel<false, true><<<dim3(64, 6), 256, 0, stream>>>(
        xcat, WoT, d_out, b_o, 8192, 768, 1536, 1536, 1536, 768);
}

// Round 3
// 554.791 us; speedup vs baseline: 1.0038x; 1.0038x over previous
//
#include <hip/hip_runtime.h>
#include <math.h>

// ---------------------------------------------------------------------------
// DynamicAttention4 (B=32 L=256 S=T=64 H=768 Q=768 F=1024 OUT=768)
// q=query@Wq+bq; s_key=src@Ws+bs; t_key=trg@Wt+bt
// rel_key[b,t,s,:]=tanh(s_key[b,s,:]+t_key[b,t,:])
// scores[b,l,ts]=q·rel_key/sqrt(768); softmax over ts=4096
// ctx[b,l,:]=sum_ts w*rel_key; out=relu([query,ctx]@Wo+bo)
//
// FAST path (ws >= 340MB): relkT = rel_key^T (h-major) materialized bf16 once;
//   ctx = pure batched BT-GEMM. scores keeps fused tanh (only 24 k-steps).
// FALLBACK path: round-1 fully-fused pipeline (proven) if ws is small.
// ---------------------------------------------------------------------------

typedef __attribute__((ext_vector_type(8))) short bf16x8;
typedef __attribute__((ext_vector_type(4))) float f32x4;

__device__ __forceinline__ unsigned short f2bf(float f) {
    union { float f; unsigned u; } x; x.f = f;
    unsigned u = x.u;
    return (unsigned short)((u + 0x7fffu + ((u >> 16) & 1u)) >> 16);
}
__device__ __forceinline__ float bf2f(unsigned short h) {
    union { unsigned u; float f; } x; x.u = (unsigned)h << 16;
    return x.f;
}
__device__ __forceinline__ float tanh_fast(float x) {
    float e = __expf(2.0f * x);
    return 1.0f - 2.0f * __builtin_amdgcn_rcpf(1.0f + e);
}
__device__ __forceinline__ void async_copy16(void* lds, const void* g) {
    __builtin_amdgcn_global_load_lds(
        (const __attribute__((address_space(1))) unsigned int*)g,
        (__attribute__((address_space(3))) unsigned int*)lds,
        16, 0, 0);
}

// ---------------------------------------------------------------------------
// Batched bf16 BT-GEMM: C[z][m,n] = sum_k A[z][m,k]*BT[z][n,k] (+bias,+relu)
// 128x128 tile, BK=32, 4 waves, 4x4 16x16x32 frags. Same k-map for A/B.
// ---------------------------------------------------------------------------
template<bool OUT_BF16, bool RELU>
__global__ __launch_bounds__(256, 2) void gemm_bt_kernel(
    const unsigned short* __restrict__ A, const unsigned short* __restrict__ BT,
    void* __restrict__ Cout, const float* __restrict__ bias,
    int M, int N, int K, int lda, int ldb, int ldc,
    long long sA, long long sB, long long sC)
{
    __shared__ unsigned short As[128 * 32];
    __shared__ unsigned short Bs[128 * 32];
    const int z = blockIdx.z;
    A  += (long long)z * sA;
    BT += (long long)z * sB;
    const int m0 = blockIdx.x * 128, n0 = blockIdx.y * 128;
    const int tid = threadIdx.x;
    const int lane = tid & 63, wid = tid >> 6;
    const int wr = wid >> 1, wc = wid & 1;
    const int r = lane & 15, g = lane >> 4;

    f32x4 acc[4][4] = {};

    for (int k0 = 0; k0 < K; k0 += 32) {
        __syncthreads();
        #pragma unroll
        for (int j = 0; j < 2; ++j) {
            int c = j * 256 + tid;
            int row = c >> 2, kc = (c & 3) * 8;
            async_copy16(&As[c * 8], A  + (size_t)(m0 + row) * lda + k0 + kc);
            async_copy16(&Bs[c * 8], BT + (size_t)(n0 + row) * ldb + k0 + kc);
        }
        asm volatile("s_waitcnt vmcnt(0)" ::: "memory");
        __syncthreads();

        bf16x8 af[4], bfr[4];
        #pragma unroll
        for (int m = 0; m < 4; ++m)
            af[m] = *(const bf16x8*)&As[(wr * 64 + m * 16 + r) * 32 + g * 8];
        #pragma unroll
        for (int n = 0; n < 4; ++n)
            bfr[n] = *(const bf16x8*)&Bs[(wc * 64 + n * 16 + r) * 32 + g * 8];
        #pragma unroll
        for (int m = 0; m < 4; ++m)
            #pragma unroll
            for (int n = 0; n < 4; ++n)
                acc[m][n] = __builtin_amdgcn_mfma_f32_16x16x32_bf16(
                    af[m], bfr[n], acc[m][n], 0, 0, 0);
    }

    float* Cf = (float*)Cout;
    unsigned short* Cb = (unsigned short*)Cout;
    const long long cbase = (long long)z * sC;
    #pragma unroll
    for (int n = 0; n < 4; ++n) {
        int col = n0 + wc * 64 + n * 16 + r;
        float bv = bias ? bias[col] : 0.0f;
        #pragma unroll
        for (int m = 0; m < 4; ++m) {
            int row0 = m0 + wr * 64 + m * 16 + g * 4;
            #pragma unroll
            for (int i = 0; i < 4; ++i) {
                float v = acc[m][n][i] + bv;
                if (RELU) v = fmaxf(v, 0.0f);
                size_t off = (size_t)cbase + (size_t)(row0 + i) * ldc + col;
                if (OUT_BF16) Cb[off] = f2bf(v);
                else          Cf[off] = v;
            }
        }
    }
}

// ---------------------------------------------------------------------------
// scores[b,l,ts] GEMM with fused rel_key B-tiles. (round-1, proven)
// ---------------------------------------------------------------------------
__global__ __launch_bounds__(256, 2) void scores_kernel(
    const unsigned short* __restrict__ qh,   // [32][256][768]
    const float* __restrict__ s_key,         // [32][64][768]
    const float* __restrict__ t_key,         // [32][64][768]
    unsigned short* __restrict__ scores)     // [32][256][4096]
{
    __shared__ unsigned short As[128 * 32];
    __shared__ unsigned short Bs[128 * 32];
    __shared__ float Sk[64 * 32];
    __shared__ float Tk[64];

    const int b = blockIdx.z;
    const unsigned short* A = qh + (size_t)b * 256 * 768;
    const float* skp = s_key + (size_t)b * 64 * 768;
    const float* tkp = t_key + (size_t)b * 64 * 768;
    const int m0 = blockIdx.x * 128, n0 = blockIdx.y * 128;
    const int t0 = n0 >> 6;
    const int tid = threadIdx.x;
    const int lane = tid & 63, wid = tid >> 6;
    const int wr = wid >> 1, wc = wid & 1;
    const int r = lane & 15, g = lane >> 4;

    f32x4 acc[4][4] = {};

    for (int k0 = 0; k0 < 768; k0 += 32) {
        __syncthreads();
        if (tid < 64) Tk[tid] = tkp[(size_t)(t0 + (tid >> 5)) * 768 + k0 + (tid & 31)];
        #pragma unroll
        for (int j = 0; j < 2; ++j) {
            int c = j * 256 + tid;
            int row = c >> 2, kc = (c & 3) * 8;
            async_copy16(&As[c * 8], A + (size_t)(m0 + row) * 768 + k0 + kc);
            int s = c >> 3, k4 = (c & 7) * 4;
            async_copy16(&Sk[s * 32 + k4], skp + (size_t)s * 768 + k0 + k4);
        }
        asm volatile("s_waitcnt vmcnt(0)" ::: "memory");
        __syncthreads();

        #pragma unroll
        for (int j = 0; j < 2; ++j) {
            int c = j * 256 + tid;
            int n = c >> 2, kc = (c & 3) * 8;
            const float* sv = &Sk[(n & 63) * 32 + kc];
            const float* tv = &Tk[(n >> 6) * 32 + kc];
            bf16x8 o;
            #pragma unroll
            for (int e = 0; e < 8; ++e)
                o[e] = (short)f2bf(tanh_fast(sv[e] + tv[e]));
            *(bf16x8*)&Bs[n * 32 + kc] = o;
        }
        __syncthreads();

        bf16x8 af[4], bfr[4];
        #pragma unroll
        for (int m = 0; m < 4; ++m)
            af[m] = *(const bf16x8*)&As[(wr * 64 + m * 16 + r) * 32 + g * 8];
        #pragma unroll
        for (int n = 0; n < 4; ++n)
            bfr[n] = *(const bf16x8*)&Bs[(wc * 64 + n * 16 + r) * 32 + g * 8];
        #pragma unroll
        for (int m = 0; m < 4; ++m)
            #pragma unroll
            for (int n = 0; n < 4; ++n)
                acc[m][n] = __builtin_amdgcn_mfma_f32_16x16x32_bf16(
                    af[m], bfr[n], acc[m][n], 0, 0, 0);
    }

    unsigned short* C = scores + (size_t)b * 256 * 4096;
    #pragma unroll
    for (int n = 0; n < 4; ++n) {
        int col = n0 + wc * 64 + n * 16 + r;
        #pragma unroll
        for (int m = 0; m < 4; ++m) {
            int row0 = m0 + wr * 64 + m * 16 + g * 4;
            #pragma unroll
            for (int i = 0; i < 4; ++i)
                C[(size_t)(row0 + i) * 4096 + col] = f2bf(acc[m][n][i]);
        }
    }
}

// ---------------------------------------------------------------------------
// FALLBACK ctx kernel (round-1, fused tanh) — used only when ws is small.
// ---------------------------------------------------------------------------
__global__ __launch_bounds__(256, 2) void ctx_kernel(
    const unsigned short* __restrict__ w,
    const float* __restrict__ s_keyT,
    const float* __restrict__ t_keyT,
    unsigned short* __restrict__ xcat)
{
    __shared__ unsigned short As[128 * 32];
    __shared__ unsigned short Bs[128 * 32];
    __shared__ float SkT[128 * 32];
    __shared__ unsigned short TkTb[128 * 64];

    const int b = blockIdx.z;
    const unsigned short* A = w + (size_t)b * 256 * 4096;
    const float* skT = s_keyT + (size_t)b * 768 * 64;
    const float* tkT = t_keyT + (size_t)b * 768 * 64;
    const int m0 = blockIdx.x * 128, n0 = blockIdx.y * 128;
    const int tid = threadIdx.x;
    const int lane = tid & 63, wid = tid >> 6;
    const int wr = wid >> 1, wc = wid & 1;
    const int r = lane & 15, g = lane >> 4;

    for (int j = tid; j < 128 * 64; j += 256)
        TkTb[j] = f2bf(tkT[(size_t)n0 * 64 + j]);

    f32x4 acc[4][4] = {};

    for (int k0 = 0; k0 < 4096; k0 += 32) {
        const int t = k0 >> 6, s0 = k0 & 63;
        __syncthreads();
        #pragma unroll
        for (int j = 0; j < 2; ++j) {
            int c = j * 256 + tid;
            int row = c >> 2, kc = (c & 3) * 8;
            async_copy16(&As[c * 8], A + (size_t)(m0 + row) * 4096 + k0 + kc);
        }
        #pragma unroll
        for (int j = 0; j < 4; ++j) {
            int c = j * 256 + tid;
            int h = c >> 3, k4 = (c & 7) * 4;
            async_copy16(&SkT[h * 32 + k4], skT + (size_t)(n0 + h) * 64 + s0 + k4);
        }
        asm volatile("s_waitcnt vmcnt(0)" ::: "memory");
        __syncthreads();

        #pragma unroll
        for (int j = 0; j < 2; ++j) {
            int c = j * 256 + tid;
            int h = c >> 2, kc = (c & 3) * 8;
            const float* sv = &SkT[h * 32 + kc];
            float tval = bf2f(TkTb[h * 64 + t]);
            bf16x8 o;
            #pragma unroll
            for (int e = 0; e < 8; ++e)
                o[e] = (short)f2bf(tanh_fast(sv[e] + tval));
            *(bf16x8*)&Bs[h * 32 + kc] = o;
        }
        __syncthreads();

        bf16x8 af[4], bfr[4];
        #pragma unroll
        for (int m = 0; m < 4; ++m)
            af[m] = *(const bf16x8*)&As[(wr * 64 + m * 16 + r) * 32 + g * 8];
        #pragma unroll
        for (int n = 0; n < 4; ++n)
            bfr[n] = *(const bf16x8*)&Bs[(wc * 64 + n * 16 + r) * 32 + g * 8];
        #pragma unroll
        for (int m = 0; m < 4; ++m)
            #pragma unroll
            for (int n = 0; n < 4; ++n)
                acc[m][n] = __builtin_amdgcn_mfma_f32_16x16x32_bf16(
                    af[m], bfr[n], acc[m][n], 0, 0, 0);
    }

    unsigned short* C = xcat + (size_t)b * 256 * 1536 + 768;
    #pragma unroll
    for (int n = 0; n < 4; ++n) {
        int col = n0 + wc * 64 + n * 16 + r;
        #pragma unroll
        for (int m = 0; m < 4; ++m) {
            int row0 = m0 + wr * 64 + m * 16 + g * 4;
            #pragma unroll
            for (int i = 0; i < 4; ++i)
                C[(size_t)(row0 + i) * 1536 + col] = f2bf(acc[m][n][i]);
        }
    }
}

// ---------------------------------------------------------------------------
// relkT kernel: relkT[b][h][ts] = bf16(tanh(s_key[b,s,h] + t_key[b,t,h]))
// one block per (b,t); LDS-transposed s_key tiles; coalesced 128B writes.
// ---------------------------------------------------------------------------
__global__ __launch_bounds__(256) void relkT_kernel(
    const float* __restrict__ s_key,         // [32][64][768]
    const float* __restrict__ t_key,         // [32][64][768]
    unsigned short* __restrict__ relkT)      // [32][768][4096]
{
    const int b = blockIdx.x >> 6, t = blockIdx.x & 63;
    const float* sk = s_key + (size_t)b * 64 * 768;
    const float* tk = t_key + ((size_t)b * 64 + t) * 768;
    unsigned short* rkT = relkT + (size_t)b * 768 * 4096 + t * 64;
    const int tx = threadIdx.x & 63, ty = threadIdx.x >> 6;
    __shared__ float tile[64][65];   // [s][h_local]
    for (int h0 = 0; h0 < 768; h0 += 64) {
        for (int s = ty; s < 64; s += 4)
            tile[s][tx] = sk[(size_t)s * 768 + h0 + tx];
        __syncthreads();
        for (int h = ty; h < 64; h += 4) {
            float tval = tk[h0 + h];
            rkT[(size_t)(h0 + h) * 4096 + tx] = f2bf(tanh_fast(tile[tx][h] + tval));
        }
        __syncthreads();
    }
}

// ---------------------------------------------------------------------------
// converters / transposes
// ---------------------------------------------------------------------------
__global__ void cvt_bf16_kernel(const float* __restrict__ in,
                                unsigned short* __restrict__ out, int n4) {
    int i = blockIdx.x * 256 + threadIdx.x;
    if (i >= n4) return;
    float4 v = ((const float4*)in)[i];
    ushort4 o;
    o.x = f2bf(v.x); o.y = f2bf(v.y); o.z = f2bf(v.z); o.w = f2bf(v.w);
    ((ushort4*)out)[i] = o;
}

__global__ void cvt_query_kernel(const float* __restrict__ in,
                                 unsigned short* __restrict__ xcat) {
    int i = blockIdx.x * 256 + threadIdx.x;
    if (i >= 8192 * 192) return;
    int row = i / 192, c4 = (i % 192) * 4;
    float4 v = ((const float4*)in)[i];
    ushort4 o;
    o.x = f2bf(v.x); o.y = f2bf(v.y); o.z = f2bf(v.z); o.w = f2bf(v.w);
    *(ushort4*)&xcat[(size_t)row * 1536 + c4] = o;
}

__global__ void transpose_w_kernel(const float* __restrict__ in,
                                   unsigned short* __restrict__ out,
                                   int R, int C) {
    __shared__ float tile[64][65];
    const int r0 = blockIdx.y * 64, c0 = blockIdx.x * 64;
    const int tx = threadIdx.x & 63, ty = threadIdx.x >> 6;
    for (int i = ty; i < 64; i += 4)
        tile[i][tx] = in[(size_t)(r0 + i) * C + c0 + tx];
    __syncthreads();
    for (int i = ty; i < 64; i += 4)
        out[(size_t)(c0 + i) * R + r0 + tx] = f2bf(tile[tx][i]);
}

__global__ void transpose_sk_kernel(const float* __restrict__ in,
                                    float* __restrict__ out) {
    __shared__ float tile[64][65];
    const int b = blockIdx.y, c0 = blockIdx.x * 64;
    const float* src = in + (size_t)b * 64 * 768;
    float* dst = out + (size_t)b * 768 * 64;
    const int tx = threadIdx.x & 63, ty = threadIdx.x >> 6;
    for (int i = ty; i < 64; i += 4)
        tile[i][tx] = src[(size_t)i * 768 + c0 + tx];
    __syncthreads();
    for (int i = ty; i < 64; i += 4)
        dst[(size_t)(c0 + i) * 64 + tx] = tile[tx][i];
}

// ---------------------------------------------------------------------------
// row softmax over 4096 (bf16 in-place), scale 1/sqrt(768) before exp
// ---------------------------------------------------------------------------
__global__ __launch_bounds__(256) void softmax_kernel(unsigned short* __restrict__ scores) {
    unsigned short* p = scores + (size_t)blockIdx.x * 4096;
    const int tid = threadIdx.x, lane = tid & 63, wid = tid >> 6;
    __shared__ float red[4];

    float v[16];
    {
        const bf16x8* p8 = (const bf16x8*)p;
        bf16x8 a = p8[tid * 2], c = p8[tid * 2 + 1];
        #pragma unroll
        for (int e = 0; e < 8; ++e) {
            v[e]     = bf2f((unsigned short)a[e]);
            v[8 + e] = bf2f((unsigned short)c[e]);
        }
    }
    float mx = v[0];
    #pragma unroll
    for (int e = 1; e < 16; ++e) mx = fmaxf(mx, v[e]);
    #pragma unroll
    for (int o = 32; o; o >>= 1) mx = fmaxf(mx, __shfl_xor(mx, o));
    if (lane == 0) red[wid] = mx;
    __syncthreads();
    mx = fmaxf(fmaxf(red[0], red[1]), fmaxf(red[2], red[3]));
    __syncthreads();

    const float scale = 0.03608439182435161f;   // 1/sqrt(768)
    float sum = 0.0f;
    #pragma unroll
    for (int e = 0; e < 16; ++e) {
        v[e] = __expf((v[e] - mx) * scale);
        sum += v[e];
    }
    #pragma unroll
    for (int o = 32; o; o >>= 1) sum += __shfl_xor(sum, o);
    if (lane == 0) red[wid] = sum;
    __syncthreads();
    sum = red[0] + red[1] + red[2] + red[3];
    const float inv = 1.0f / sum;

    bf16x8* p8 = (bf16x8*)p;
    #pragma unroll
    for (int j = 0; j < 2; ++j) {
        bf16x8 o;
        #pragma unroll
        for (int e = 0; e < 8; ++e)
            o[e] = (short)f2bf(v[j * 8 + e] * inv);
        p8[tid * 2 + j] = o;
    }
}

// ---------------------------------------------------------------------------
extern "C" void kernel_launch(void* const* d_in, const int* in_sizes, int n_in,
                              void* d_out, int out_size, void* d_ws, size_t ws_size,
                              hipStream_t stream) {
    const float* query = (const float*)d_in[0];
    const float* src   = (const float*)d_in[1];
    const float* trg   = (const float*)d_in[2];
    const float* Wq    = (const float*)d_in[3];
    const float* b_q   = (const float*)d_in[4];
    const float* Ws    = (const float*)d_in[5];
    const float* b_s   = (const float*)d_in[6];
    const float* Wt    = (const float*)d_in[7];
    const float* b_t   = (const float*)d_in[8];
    const float* Wo    = (const float*)d_in[9];
    const float* b_o   = (const float*)d_in[10];

    char* ws = (char*)d_ws;
    size_t off = 0;
    auto alloc = [&](size_t bytes) {
        void* p = ws + off;
        off += (bytes + 255) & ~(size_t)255;
        return p;
    };
    // common buffers (both paths)
    unsigned short* xcat   = (unsigned short*)alloc((size_t)8192 * 1536 * 2);
    unsigned short* srcbf  = (unsigned short*)alloc((size_t)2048 * 1024 * 2);
    unsigned short* trgbf  = (unsigned short*)alloc((size_t)2048 * 1024 * 2);
    unsigned short* WqT    = (unsigned short*)alloc((size_t)768 * 768 * 2);
    unsigned short* WsT    = (unsigned short*)alloc((size_t)768 * 1024 * 2);
    unsigned short* WtT    = (unsigned short*)alloc((size_t)768 * 1024 * 2);
    unsigned short* WoT    = (unsigned short*)alloc((size_t)768 * 1536 * 2);
    unsigned short* qh     = (unsigned short*)alloc((size_t)8192 * 768 * 2);
    float*          s_key  = (float*)alloc((size_t)2048 * 768 * 4);
    float*          t_key  = (float*)alloc((size_t)2048 * 768 * 4);
    unsigned short* scores = (unsigned short*)alloc((size_t)32 * 256 * 4096 * 2);

    const bool fast = ws_size >= 340000000ULL;   // fast path needs ~334 MB

    unsigned short* relkT  = nullptr;   // fast only: [32][768][4096] bf16
    float* s_keyT = nullptr, * t_keyT = nullptr;  // fallback only
    if (fast) {
        relkT = (unsigned short*)alloc((size_t)32 * 768 * 4096 * 2);
    } else {
        s_keyT = (float*)alloc((size_t)32 * 768 * 64 * 4);
        t_keyT = (float*)alloc((size_t)32 * 768 * 64 * 4);
    }

    // 1. input converts
    cvt_query_kernel<<<6144, 256, 0, stream>>>(query, xcat);
    cvt_bf16_kernel<<<2048, 256, 0, stream>>>(src, srcbf, 524288);
    cvt_bf16_kernel<<<2048, 256, 0, stream>>>(trg, trgbf, 524288);

    // 2. weight transposes
    transpose_w_kernel<<<dim3(12, 12), 256, 0, stream>>>(Wq, WqT, 768, 768);
    transpose_w_kernel<<<dim3(12, 16), 256, 0, stream>>>(Ws, WsT, 1024, 768);
    transpose_w_kernel<<<dim3(12, 16), 256, 0, stream>>>(Wt, WtT, 1024, 768);
    transpose_w_kernel<<<dim3(12, 24), 256, 0, stream>>>(Wo, WoT, 1536, 768);

    // 3. projections
    gemm_bt_kernel<true, false><<<dim3(64, 6, 1), 256, 0, stream>>>(
        xcat, WqT, qh, b_q, 8192, 768, 768, 1536, 768, 768, 0, 0, 0);
    gemm_bt_kernel<false, false><<<dim3(16, 6, 1), 256, 0, stream>>>(
        srcbf, WsT, s_key, b_s, 2048, 768, 1024, 1024, 1024, 768, 0, 0, 0);
    gemm_bt_kernel<false, false><<<dim3(16, 6, 1), 256, 0, stream>>>(
        trgbf, WtT, t_key, b_t, 2048, 768, 1024, 1024, 1024, 768, 0, 0, 0);

    if (fast) {
        // 4. materialize rel_key^T (h-major) bf16, tanh computed exactly once
        relkT_kernel<<<2048, 256, 0, stream>>>(s_key, t_key, relkT);
    } else {
        transpose_sk_kernel<<<dim3(12, 32), 256, 0, stream>>>(s_key, s_keyT);
        transpose_sk_kernel<<<dim3(12, 32), 256, 0, stream>>>(t_key, t_keyT);
    }

    // 5. scores (fused rel_key tanh, 24 k-steps), bf16
    scores_kernel<<<dim3(2, 32, 32), 256, 0, stream>>>(qh, s_key, t_key, scores);

    // 6. softmax in-place
    softmax_kernel<<<8192, 256, 0, stream>>>(scores);

    // 7. ctx -> xcat[:, 768:]
    if (fast) {
        // pure batched BT-GEMM: A=w[b] (256x4096), BT=relkT[b] (768x4096)
        gemm_bt_kernel<true, false><<<dim3(2, 6, 32), 256, 0, stream>>>(
            scores, relkT, xcat + 768, nullptr,
            256, 768, 4096, 4096, 4096, 1536,
            256LL * 4096, 768LL * 4096, 256LL * 1536);
    } else {
        ctx_kernel<<<dim3(2, 6, 32), 256, 0, stream>>>(scores, s_keyT, t_keyT, xcat);
    }

    // 8. out = relu(xcat @ WoT^T + b_o)
    gemm_bt_kernel<false, true><<<dim3(64, 6, 1), 256, 0, stream>>>(
        xcat, WoT, d_out, b_o, 8192, 768, 1536, 1536, 1536, 768, 0, 0, 0);
}

// Round 4
// 513.766 us; speedup vs baseline: 1.0840x; 1.0799x over previous
//
#include <hip/hip_runtime.h>
#include <math.h>

// ---------------------------------------------------------------------------
// DynamicAttention4 (B=32 L=256 S=T=64 H=768 Q=768 F=1024 OUT=768)
// q=query@Wq+bq; s_key=src@Ws+bs; t_key=trg@Wt+bt
// rel_key[b,t,s,:]=tanh(s_key[b,s,:]+t_key[b,t,:])   (never materialized)
// scores[b,l,ts]=q·rel_key/sqrt(768); softmax over ts=4096
// ctx[b,l,:]=sum_ts w*rel_key; out=relu([query,ctx]@Wo+bo)
//
// Round-3: bank-conflict-free fused B-tile builds.
//  - ctx: s_key slab staged once per block into padded LDS (stride 132 f32);
//    tanh built h-contiguous, transpose-scattered into Bs (stride 40 bf16).
//  - scores: reg-staged padded Sk (stride 36 f32); Bs stride 40.
// Workspace ~133 MB (known-safe; no 340MB path).
// ---------------------------------------------------------------------------

typedef __attribute__((ext_vector_type(8))) short bf16x8;
typedef __attribute__((ext_vector_type(4))) float f32x4;

__device__ __forceinline__ unsigned short f2bf(float f) {
    union { float f; unsigned u; } x; x.f = f;
    unsigned u = x.u;
    return (unsigned short)((u + 0x7fffu + ((u >> 16) & 1u)) >> 16);
}
__device__ __forceinline__ float bf2f(unsigned short h) {
    union { unsigned u; float f; } x; x.u = (unsigned)h << 16;
    return x.f;
}
__device__ __forceinline__ float tanh_fast(float x) {
    float e = __expf(2.0f * x);
    return 1.0f - 2.0f * __builtin_amdgcn_rcpf(1.0f + e);
}
__device__ __forceinline__ void async_copy16(void* lds, const void* g) {
    __builtin_amdgcn_global_load_lds(
        (const __attribute__((address_space(1))) unsigned int*)g,
        (__attribute__((address_space(3))) unsigned int*)lds,
        16, 0, 0);
}

// ---------------------------------------------------------------------------
// Batched bf16 BT-GEMM: C[z][m,n] = sum_k A[z][m,k]*BT[z][n,k] (+bias,+relu)
// 128x128 tile, BK=32, 4 waves, 4x4 16x16x32 frags. Same k-map for A/B.
// ---------------------------------------------------------------------------
template<bool OUT_BF16, bool RELU>
__global__ __launch_bounds__(256, 2) void gemm_bt_kernel(
    const unsigned short* __restrict__ A, const unsigned short* __restrict__ BT,
    void* __restrict__ Cout, const float* __restrict__ bias,
    int M, int N, int K, int lda, int ldb, int ldc,
    long long sA, long long sB, long long sC)
{
    __shared__ unsigned short As[128 * 32];
    __shared__ unsigned short Bs[128 * 32];
    const int z = blockIdx.z;
    A  += (long long)z * sA;
    BT += (long long)z * sB;
    const int m0 = blockIdx.x * 128, n0 = blockIdx.y * 128;
    const int tid = threadIdx.x;
    const int lane = tid & 63, wid = tid >> 6;
    const int wr = wid >> 1, wc = wid & 1;
    const int r = lane & 15, g = lane >> 4;

    f32x4 acc[4][4] = {};

    for (int k0 = 0; k0 < K; k0 += 32) {
        __syncthreads();
        #pragma unroll
        for (int j = 0; j < 2; ++j) {
            int c = j * 256 + tid;
            int row = c >> 2, kc = (c & 3) * 8;
            async_copy16(&As[c * 8], A  + (size_t)(m0 + row) * lda + k0 + kc);
            async_copy16(&Bs[c * 8], BT + (size_t)(n0 + row) * ldb + k0 + kc);
        }
        asm volatile("s_waitcnt vmcnt(0)" ::: "memory");
        __syncthreads();

        bf16x8 af[4], bfr[4];
        #pragma unroll
        for (int m = 0; m < 4; ++m)
            af[m] = *(const bf16x8*)&As[(wr * 64 + m * 16 + r) * 32 + g * 8];
        #pragma unroll
        for (int n = 0; n < 4; ++n)
            bfr[n] = *(const bf16x8*)&Bs[(wc * 64 + n * 16 + r) * 32 + g * 8];
        #pragma unroll
        for (int m = 0; m < 4; ++m)
            #pragma unroll
            for (int n = 0; n < 4; ++n)
                acc[m][n] = __builtin_amdgcn_mfma_f32_16x16x32_bf16(
                    af[m], bfr[n], acc[m][n], 0, 0, 0);
    }

    float* Cf = (float*)Cout;
    unsigned short* Cb = (unsigned short*)Cout;
    const long long cbase = (long long)z * sC;
    #pragma unroll
    for (int n = 0; n < 4; ++n) {
        int col = n0 + wc * 64 + n * 16 + r;
        float bv = bias ? bias[col] : 0.0f;
        #pragma unroll
        for (int m = 0; m < 4; ++m) {
            int row0 = m0 + wr * 64 + m * 16 + g * 4;
            #pragma unroll
            for (int i = 0; i < 4; ++i) {
                float v = acc[m][n][i] + bv;
                if (RELU) v = fmaxf(v, 0.0f);
                size_t off = (size_t)cbase + (size_t)(row0 + i) * ldc + col;
                if (OUT_BF16) Cb[off] = f2bf(v);
                else          Cf[off] = v;
            }
        }
    }
}

// ---------------------------------------------------------------------------
// scores[b,l,ts] GEMM with fused rel_key B-tiles (conflict-free build).
// A = qh[b] (256x768 bf16), B[n=ts][k=h] = tanh(s_key[s,h]+t_key[t,h]).
// grid (2, 32, 32) = (m-tiles, ts-tiles, batch)
// ---------------------------------------------------------------------------
__global__ __launch_bounds__(256, 2) void scores_kernel(
    const unsigned short* __restrict__ qh,   // [32][256][768]
    const float* __restrict__ s_key,         // [32][64][768]
    const float* __restrict__ t_key,         // [32][64][768]
    unsigned short* __restrict__ scores)     // [32][256][4096]
{
    __shared__ unsigned short As[128 * 32];
    __shared__ unsigned short Bs[128 * 40];  // padded stride 40 shorts
    __shared__ float Sk[64 * 36];            // padded stride 36 floats
    __shared__ float Tk[2 * 32];

    const int b = blockIdx.z;
    const unsigned short* A = qh + (size_t)b * 256 * 768;
    const float* skp = s_key + (size_t)b * 64 * 768;
    const float* tkp = t_key + (size_t)b * 64 * 768;
    const int m0 = blockIdx.x * 128, n0 = blockIdx.y * 128;
    const int t0 = n0 >> 6;                  // two t values per 128-ts tile
    const int tid = threadIdx.x;
    const int lane = tid & 63, wid = tid >> 6;
    const int wr = wid >> 1, wc = wid & 1;
    const int r = lane & 15, g = lane >> 4;

    f32x4 acc[4][4] = {};

    for (int k0 = 0; k0 < 768; k0 += 32) {
        __syncthreads();
        if (tid < 64) Tk[tid] = tkp[(size_t)(t0 + (tid >> 5)) * 768 + k0 + (tid & 31)];
        #pragma unroll
        for (int j = 0; j < 2; ++j) {
            int c = j * 256 + tid;
            int row = c >> 2, kc = (c & 3) * 8;
            async_copy16(&As[c * 8], A + (size_t)(m0 + row) * 768 + k0 + kc);
        }
        // reg-stage s_key chunk into padded Sk: [64 s][32 k], stride 36
        {
            int s = tid >> 2, c4 = (tid & 3) * 8;
            float4 v0 = *(const float4*)&skp[(size_t)s * 768 + k0 + c4];
            float4 v1 = *(const float4*)&skp[(size_t)s * 768 + k0 + c4 + 4];
            *(float4*)&Sk[s * 36 + c4]     = v0;
            *(float4*)&Sk[s * 36 + c4 + 4] = v1;
        }
        asm volatile("s_waitcnt vmcnt(0)" ::: "memory");
        __syncthreads();

        // Bs[n][kk] = bf16(tanh(Sk[n&63][kk] + Tk[n>>6][kk]))
        #pragma unroll
        for (int j = 0; j < 2; ++j) {
            int c = j * 256 + tid;
            int n = c >> 2, kc = (c & 3) * 8;
            const float* sv = &Sk[(n & 63) * 36 + kc];
            const float* tv = &Tk[(n >> 6) * 32 + kc];
            bf16x8 o;
            #pragma unroll
            for (int e = 0; e < 8; ++e)
                o[e] = (short)f2bf(tanh_fast(sv[e] + tv[e]));
            *(bf16x8*)&Bs[n * 40 + kc] = o;
        }
        __syncthreads();

        bf16x8 af[4], bfr[4];
        #pragma unroll
        for (int m = 0; m < 4; ++m)
            af[m] = *(const bf16x8*)&As[(wr * 64 + m * 16 + r) * 32 + g * 8];
        #pragma unroll
        for (int n = 0; n < 4; ++n)
            bfr[n] = *(const bf16x8*)&Bs[(wc * 64 + n * 16 + r) * 40 + g * 8];
        #pragma unroll
        for (int m = 0; m < 4; ++m)
            #pragma unroll
            for (int n = 0; n < 4; ++n)
                acc[m][n] = __builtin_amdgcn_mfma_f32_16x16x32_bf16(
                    af[m], bfr[n], acc[m][n], 0, 0, 0);
    }

    unsigned short* C = scores + (size_t)b * 256 * 4096;
    #pragma unroll
    for (int n = 0; n < 4; ++n) {
        int col = n0 + wc * 64 + n * 16 + r;
        #pragma unroll
        for (int m = 0; m < 4; ++m) {
            int row0 = m0 + wr * 64 + m * 16 + g * 4;
            #pragma unroll
            for (int i = 0; i < 4; ++i)
                C[(size_t)(row0 + i) * 4096 + col] = f2bf(acc[m][n][i]);
        }
    }
}

// ---------------------------------------------------------------------------
// ctx[b,l,h] GEMM with fused rel_key B-tiles, conflict-free transposed build.
// A = w[b] (256x4096 bf16), B[n=h][k=ts] = tanh(s_key[s,h]+t_key[t,h]).
// s_key slab [64s][128h] staged once per block (padded stride 132 f32);
// build reads h-contiguous (balanced), scatters into Bs stride 40.
// grid (2, 6, 32). Writes bf16 into xcat[:, 768:1536].
// ---------------------------------------------------------------------------
__global__ __launch_bounds__(256, 2) void ctx_kernel(
    const unsigned short* __restrict__ w,    // [32][256][4096]
    const float* __restrict__ s_key,         // [32][64][768]
    const float* __restrict__ t_key,         // [32][64][768]
    unsigned short* __restrict__ xcat)       // [8192][1536]
{
    __shared__ unsigned short As[128 * 32];
    __shared__ unsigned short Bs[128 * 40];  // padded stride 40 shorts
    __shared__ float Sk[64 * 132];           // [s][h] padded stride 132 floats

    const int b = blockIdx.z;
    const unsigned short* A = w + (size_t)b * 256 * 4096;
    const float* skp = s_key + (size_t)b * 64 * 768;
    const float* tkp = t_key + (size_t)b * 64 * 768;
    const int m0 = blockIdx.x * 128, n0 = blockIdx.y * 128;
    const int tid = threadIdx.x;
    const int lane = tid & 63, wid = tid >> 6;
    const int wr = wid >> 1, wc = wid & 1;
    const int r = lane & 15, g = lane >> 4;

    // stage s_key slab for this h-window once: [64 s][128 h] fp32, padded
    #pragma unroll
    for (int it = 0; it < 8; ++it) {
        int idx = it * 256 + tid;            // 2048 float4 chunks
        int s = idx >> 5, c4 = (idx & 31) * 4;
        *(float4*)&Sk[s * 132 + c4] = *(const float4*)&skp[(size_t)s * 768 + n0 + c4];
    }

    const int sl = tid & 31;                 // k-position within 32-chunk
    const int hq = tid >> 5;                 // 0..7

    f32x4 acc[4][4] = {};
    __syncthreads();

    for (int k0 = 0; k0 < 4096; k0 += 32) {
        const int t = k0 >> 6, s0 = k0 & 63; // ts = t*64 + (s0..s0+31)
        __syncthreads();
        #pragma unroll
        for (int j = 0; j < 2; ++j) {
            int c = j * 256 + tid;
            int row = c >> 2, kc = (c & 3) * 8;
            async_copy16(&As[c * 8], A + (size_t)(m0 + row) * 4096 + k0 + kc);
        }
        // build Bs[h][sl] = tanh(Sk[s0+sl][h] + tk[t][h]), h-contiguous per thread
        #pragma unroll
        for (int j = 0; j < 2; ++j) {
            int h0 = (j * 8 + hq) * 8;       // 0..120 step 8
            int s = s0 + sl;
            float4 sa = *(const float4*)&Sk[s * 132 + h0];
            float4 sb = *(const float4*)&Sk[s * 132 + h0 + 4];
            float4 ta = *(const float4*)&tkp[(size_t)t * 768 + n0 + h0];
            float4 tb = *(const float4*)&tkp[(size_t)t * 768 + n0 + h0 + 4];
            unsigned short o0 = f2bf(tanh_fast(sa.x + ta.x));
            unsigned short o1 = f2bf(tanh_fast(sa.y + ta.y));
            unsigned short o2 = f2bf(tanh_fast(sa.z + ta.z));
            unsigned short o3 = f2bf(tanh_fast(sa.w + ta.w));
            unsigned short o4 = f2bf(tanh_fast(sb.x + tb.x));
            unsigned short o5 = f2bf(tanh_fast(sb.y + tb.y));
            unsigned short o6 = f2bf(tanh_fast(sb.z + tb.z));
            unsigned short o7 = f2bf(tanh_fast(sb.w + tb.w));
            Bs[(h0 + 0) * 40 + sl] = o0;
            Bs[(h0 + 1) * 40 + sl] = o1;
            Bs[(h0 + 2) * 40 + sl] = o2;
            Bs[(h0 + 3) * 40 + sl] = o3;
            Bs[(h0 + 4) * 40 + sl] = o4;
            Bs[(h0 + 5) * 40 + sl] = o5;
            Bs[(h0 + 6) * 40 + sl] = o6;
            Bs[(h0 + 7) * 40 + sl] = o7;
        }
        asm volatile("s_waitcnt vmcnt(0)" ::: "memory");
        __syncthreads();

        bf16x8 af[4], bfr[4];
        #pragma unroll
        for (int m = 0; m < 4; ++m)
            af[m] = *(const bf16x8*)&As[(wr * 64 + m * 16 + r) * 32 + g * 8];
        #pragma unroll
        for (int n = 0; n < 4; ++n)
            bfr[n] = *(const bf16x8*)&Bs[(wc * 64 + n * 16 + r) * 40 + g * 8];
        #pragma unroll
        for (int m = 0; m < 4; ++m)
            #pragma unroll
            for (int n = 0; n < 4; ++n)
                acc[m][n] = __builtin_amdgcn_mfma_f32_16x16x32_bf16(
                    af[m], bfr[n], acc[m][n], 0, 0, 0);
    }

    unsigned short* C = xcat + (size_t)b * 256 * 1536 + 768;
    #pragma unroll
    for (int n = 0; n < 4; ++n) {
        int col = n0 + wc * 64 + n * 16 + r;
        #pragma unroll
        for (int m = 0; m < 4; ++m) {
            int row0 = m0 + wr * 64 + m * 16 + g * 4;
            #pragma unroll
            for (int i = 0; i < 4; ++i)
                C[(size_t)(row0 + i) * 1536 + col] = f2bf(acc[m][n][i]);
        }
    }
}

// ---------------------------------------------------------------------------
// converters / transposes
// ---------------------------------------------------------------------------
__global__ void cvt_bf16_kernel(const float* __restrict__ in,
                                unsigned short* __restrict__ out, int n4) {
    int i = blockIdx.x * 256 + threadIdx.x;
    if (i >= n4) return;
    float4 v = ((const float4*)in)[i];
    ushort4 o;
    o.x = f2bf(v.x); o.y = f2bf(v.y); o.z = f2bf(v.z); o.w = f2bf(v.w);
    ((ushort4*)out)[i] = o;
}

__global__ void cvt_query_kernel(const float* __restrict__ in,
                                 unsigned short* __restrict__ xcat) {
    int i = blockIdx.x * 256 + threadIdx.x;
    if (i >= 8192 * 192) return;
    int row = i / 192, c4 = (i % 192) * 4;
    float4 v = ((const float4*)in)[i];
    ushort4 o;
    o.x = f2bf(v.x); o.y = f2bf(v.y); o.z = f2bf(v.z); o.w = f2bf(v.w);
    *(ushort4*)&xcat[(size_t)row * 1536 + c4] = o;
}

__global__ void transpose_w_kernel(const float* __restrict__ in,
                                   unsigned short* __restrict__ out,
                                   int R, int C) {
    __shared__ float tile[64][65];
    const int r0 = blockIdx.y * 64, c0 = blockIdx.x * 64;
    const int tx = threadIdx.x & 63, ty = threadIdx.x >> 6;
    for (int i = ty; i < 64; i += 4)
        tile[i][tx] = in[(size_t)(r0 + i) * C + c0 + tx];
    __syncthreads();
    for (int i = ty; i < 64; i += 4)
        out[(size_t)(c0 + i) * R + r0 + tx] = f2bf(tile[tx][i]);
}

// ---------------------------------------------------------------------------
// row softmax over 4096 (bf16 in-place), scale 1/sqrt(768) before exp
// ---------------------------------------------------------------------------
__global__ __launch_bounds__(256) void softmax_kernel(unsigned short* __restrict__ scores) {
    unsigned short* p = scores + (size_t)blockIdx.x * 4096;
    const int tid = threadIdx.x, lane = tid & 63, wid = tid >> 6;
    __shared__ float red[4];

    float v[16];
    {
        const bf16x8* p8 = (const bf16x8*)p;
        bf16x8 a = p8[tid * 2], c = p8[tid * 2 + 1];
        #pragma unroll
        for (int e = 0; e < 8; ++e) {
            v[e]     = bf2f((unsigned short)a[e]);
            v[8 + e] = bf2f((unsigned short)c[e]);
        }
    }
    float mx = v[0];
    #pragma unroll
    for (int e = 1; e < 16; ++e) mx = fmaxf(mx, v[e]);
    #pragma unroll
    for (int o = 32; o; o >>= 1) mx = fmaxf(mx, __shfl_xor(mx, o));
    if (lane == 0) red[wid] = mx;
    __syncthreads();
    mx = fmaxf(fmaxf(red[0], red[1]), fmaxf(red[2], red[3]));
    __syncthreads();

    const float scale = 0.03608439182435161f;   // 1/sqrt(768)
    float sum = 0.0f;
    #pragma unroll
    for (int e = 0; e < 16; ++e) {
        v[e] = __expf((v[e] - mx) * scale);
        sum += v[e];
    }
    #pragma unroll
    for (int o = 32; o; o >>= 1) sum += __shfl_xor(sum, o);
    if (lane == 0) red[wid] = sum;
    __syncthreads();
    sum = red[0] + red[1] + red[2] + red[3];
    const float inv = 1.0f / sum;

    bf16x8* p8 = (bf16x8*)p;
    #pragma unroll
    for (int j = 0; j < 2; ++j) {
        bf16x8 o;
        #pragma unroll
        for (int e = 0; e < 8; ++e)
            o[e] = (short)f2bf(v[j * 8 + e] * inv);
        p8[tid * 2 + j] = o;
    }
}

// ---------------------------------------------------------------------------
extern "C" void kernel_launch(void* const* d_in, const int* in_sizes, int n_in,
                              void* d_out, int out_size, void* d_ws, size_t ws_size,
                              hipStream_t stream) {
    const float* query = (const float*)d_in[0];
    const float* src   = (const float*)d_in[1];
    const float* trg   = (const float*)d_in[2];
    const float* Wq    = (const float*)d_in[3];
    const float* b_q   = (const float*)d_in[4];
    const float* Ws    = (const float*)d_in[5];
    const float* b_s   = (const float*)d_in[6];
    const float* Wt    = (const float*)d_in[7];
    const float* b_t   = (const float*)d_in[8];
    const float* Wo    = (const float*)d_in[9];
    const float* b_o   = (const float*)d_in[10];

    char* ws = (char*)d_ws;
    size_t off = 0;
    auto alloc = [&](size_t bytes) {
        void* p = ws + off;
        off += (bytes + 255) & ~(size_t)255;
        return p;
    };
    unsigned short* xcat   = (unsigned short*)alloc((size_t)8192 * 1536 * 2);
    unsigned short* srcbf  = (unsigned short*)alloc((size_t)2048 * 1024 * 2);
    unsigned short* trgbf  = (unsigned short*)alloc((size_t)2048 * 1024 * 2);
    unsigned short* WqT    = (unsigned short*)alloc((size_t)768 * 768 * 2);
    unsigned short* WsT    = (unsigned short*)alloc((size_t)768 * 1024 * 2);
    unsigned short* WtT    = (unsigned short*)alloc((size_t)768 * 1024 * 2);
    unsigned short* WoT    = (unsigned short*)alloc((size_t)768 * 1536 * 2);
    unsigned short* qh     = (unsigned short*)alloc((size_t)8192 * 768 * 2);
    float*          s_key  = (float*)alloc((size_t)2048 * 768 * 4);
    float*          t_key  = (float*)alloc((size_t)2048 * 768 * 4);
    unsigned short* scores = (unsigned short*)alloc((size_t)32 * 256 * 4096 * 2);
    // total ~133 MB (known-safe)

    // 1. input converts
    cvt_query_kernel<<<6144, 256, 0, stream>>>(query, xcat);
    cvt_bf16_kernel<<<2048, 256, 0, stream>>>(src, srcbf, 524288);
    cvt_bf16_kernel<<<2048, 256, 0, stream>>>(trg, trgbf, 524288);

    // 2. weight transposes
    transpose_w_kernel<<<dim3(12, 12), 256, 0, stream>>>(Wq, WqT, 768, 768);
    transpose_w_kernel<<<dim3(12, 16), 256, 0, stream>>>(Ws, WsT, 1024, 768);
    transpose_w_kernel<<<dim3(12, 16), 256, 0, stream>>>(Wt, WtT, 1024, 768);
    transpose_w_kernel<<<dim3(12, 24), 256, 0, stream>>>(Wo, WoT, 1536, 768);

    // 3. projections
    gemm_bt_kernel<true, false><<<dim3(64, 6, 1), 256, 0, stream>>>(
        xcat, WqT, qh, b_q, 8192, 768, 768, 1536, 768, 768, 0, 0, 0);
    gemm_bt_kernel<false, false><<<dim3(16, 6, 1), 256, 0, stream>>>(
        srcbf, WsT, s_key, b_s, 2048, 768, 1024, 1024, 1024, 768, 0, 0, 0);
    gemm_bt_kernel<false, false><<<dim3(16, 6, 1), 256, 0, stream>>>(
        trgbf, WtT, t_key, b_t, 2048, 768, 1024, 1024, 1024, 768, 0, 0, 0);

    // 4. scores (fused rel_key tanh), bf16
    scores_kernel<<<dim3(2, 32, 32), 256, 0, stream>>>(qh, s_key, t_key, scores);

    // 5. softmax in-place
    softmax_kernel<<<8192, 256, 0, stream>>>(scores);

    // 6. ctx (fused rel_key, conflict-free) -> xcat[:, 768:]
    ctx_kernel<<<dim3(2, 6, 32), 256, 0, stream>>>(scores, s_key, t_key, xcat);

    // 7. out = relu(xcat @ WoT^T + b_o)
    gemm_bt_kernel<false, true><<<dim3(64, 6, 1), 256, 0, stream>>>(
        xcat, WoT, d_out, b_o, 8192, 768, 1536, 1536, 1536, 768, 0, 0, 0);
}